// Round 5
// baseline (96.361 us; speedup 1.0000x reference)
//
#include <hip/hip_runtime.h>
#include <math.h>

#define A_    16
#define N_    1000
#define F_    16
#define E_    16000
#define D_    128
#define MAXS  65     // slot 0 = agent node, 1..64 = its in-edges
#define CAPN  48     // max tracked in-degree per slot node (Poisson(16); max@1000 nodes ~35)

__device__ __forceinline__ float lrelu(float v){ return v > 0.0f ? v : 0.2f*v; }
__device__ __forceinline__ float sigm(float x){ return 1.0f/(1.0f + expf(-x)); }

__global__ void __launch_bounds__(1024) k_fused(
    const float* __restrict__ nf, const int* __restrict__ ei,
    const float* __restrict__ hs, const int* __restrict__ am,
    const float* __restrict__ Wl1, const float* __restrict__ Wr1,
    const float* __restrict__ att1, const float* __restrict__ b1,
    const float* __restrict__ lnw, const float* __restrict__ lnb,
    const float* __restrict__ Wl2, const float* __restrict__ Wr2,
    const float* __restrict__ att2, const float* __restrict__ b2,
    const float* __restrict__ Wih, const float* __restrict__ Whh,
    const float* __restrict__ bih, const float* __restrict__ bhh,
    const float* __restrict__ Wa, const float* __restrict__ ba,
    const float* __restrict__ Wv, const float* __restrict__ bv,
    float* __restrict__ out)
{
  const int a    = blockIdx.x;
  const int tid  = threadIdx.x;
  const int lane = tid & 63;
  const int wv   = tid >> 6;          // wave 0..15
  const int c0   = lane*2;            // this lane's two channels of 128

  __shared__ float hrow[MAXS][D_];               // 33.3 KB: h1, overwritten by xl2
  __shared__ int   snbr[MAXS][CAPN];             // 12.5 KB
  __shared__ int   map_[N_];                     // 4 KB
  __shared__ int   slot_node[MAXS];
  __shared__ int   alias_[MAXS];
  __shared__ int   scnt[MAXS];
  __shared__ float tb[16][4*MAXS + 4];           // 16.9 KB per-wave softmax scratch
  __shared__ float gbuf[6*D_];
  __shared__ float xr2s[D_], afl[D_], hsl[D_], nhl[D_];
  __shared__ int   sh_da, cnt1;

  // ---- init LDS small state
  for (int t = tid; t < N_; t += 1024) map_[t] = -1;
  if (tid < MAXS){ scnt[tid] = 0; alias_[tid] = -1; }
  if (tid == 0) cnt1 = 0;

  // ---- agent-node flag scan (thread t checks node t; same thread inited map_[t])
  if (tid < N_){
    float f = nf[(size_t)(a*N_ + tid)*F_];
    if (f == 1.0f){ sh_da = tid; slot_node[0] = tid; map_[tid] = 0; }
  }

  // ---- waves 0-7: all 16000 edges -> 32 packed regs/thread (16 independent int4 loads)
  int ep[32];
  if (wv < 8){
    const int t = tid;                 // 0..511
    #pragma unroll
    for (int q = 0; q < 8; ++q){
      const int g = q*2048 + t*4;
      int4 s4, d4;
      if (g + 3 < E_){
        s4 = *(const int4*)&ei[g];
        d4 = *(const int4*)&ei[E_ + g];
      } else {
        s4 = make_int4(0,0,0,0);
        d4 = make_int4(0xFFFF,0xFFFF,0xFFFF,0xFFFF);
      }
      ep[q*4+0] = s4.x | (d4.x << 16);
      ep[q*4+1] = s4.y | (d4.y << 16);
      ep[q*4+2] = s4.z | (d4.z << 16);
      ep[q*4+3] = s4.w | (d4.w << 16);
    }
  } else {
    // ---- waves 8-15: overlap — full Whh half of the GRU + stage rnn_state
    const int t2 = tid - 512;
    if (t2 >= 384) hsl[t2 - 384] = hs[a*D_ + (t2 - 384)];
    if (t2 < 3*D_){
      const float* wrow = &Whh[t2*D_];
      const float* xg   = &hs[a*D_];
      float acc = bhh[t2];
      #pragma unroll 8
      for (int k = 0; k < D_; ++k) acc += xg[k]*wrow[k];
      gbuf[3*D_ + t2] = acc;
    }
  }
  __syncthreads();                                   // S1
  const int d_a = sh_da;

  // ---- P1: edges into agent node -> slots (from regs)
  if (wv < 8){
    #pragma unroll
    for (int q = 0; q < 32; ++q){
      const int p = ep[q];
      const unsigned dst = ((unsigned)p) >> 16;
      if ((int)dst == d_a){
        int k = atomicAdd(&cnt1, 1) + 1;
        if (k < MAXS){
          int s = p & 0xFFFF;
          slot_node[k] = s;
          int prev = atomicCAS(&map_[s], -1, k);
          if (prev != -1) alias_[k] = prev;          // duplicate src -> alias owner
        }
      }
    }
  }
  __syncthreads();                                   // S2
  const int ns = min(cnt1 + 1, MAXS);

  // ---- P2: in-edges of every owner slot node (from regs)
  if (wv < 8){
    #pragma unroll
    for (int q = 0; q < 32; ++q){
      const int p = ep[q];
      const unsigned dst = ((unsigned)p) >> 16;
      if (dst < N_){
        int o = map_[dst];
        if (o >= 0){
          int pos = atomicAdd(&scnt[o], 1);
          if (pos < CAPN) snbr[o][pos] = p & 0xFFFF;
        }
      }
    }
  }
  __syncthreads();                                   // S3

  // ---- P3: layer-1 GATv2 (4 heads x 32) two-pass softmax + LN + ReLU
  {
    float wl0[F_], wl1c[F_];
    #pragma unroll
    for (int k = 0; k < F_; ++k){
      float2 w = *(const float2*)&Wl1[k*D_ + c0];
      wl0[k] = w.x; wl1c[k] = w.y;
    }
    const int head = lane >> 4;
    const float at0 = att1[head*32 + (c0 & 31)];
    const float at1 = att1[head*32 + ((c0+1) & 31)];
    const float* nfa = &nf[(size_t)a*N_*F_];

    for (int i = wv; i < ns; i += 16){
      if (alias_[i] != -1) continue;
      const int v   = slot_node[i];
      const int deg = min(scnt[i], CAPN);
      const int nj  = deg + 1;                       // j=0 self, j>=1 neighbors
      float xr0 = 0.f, xr1 = 0.f;
      {
        const float* xd = &nfa[v*F_];
        #pragma unroll
        for (int k = 0; k < F_; ++k){
          float2 w = *(const float2*)&Wr1[k*D_ + c0];
          float xv = xd[k];
          xr0 += xv*w.x; xr1 += xv*w.y;
        }
      }
      float* tbw = tb[wv];

      // pass 1 (pairwise): scores -> tbw[4*j + head]
      int j = 0;
      for (; j + 2 <= nj; j += 2){
        const int u0 = (j == 0) ? v : snbr[i][j-1];
        const int u1 = snbr[i][j];
        const float* f0 = &nfa[u0*F_];
        const float* f1 = &nfa[u1*F_];
        float xa0=0,xa1=0,xb0=0,xb1=0;
        #pragma unroll
        for (int k = 0; k < F_; k += 4){
          float4 A = *(const float4*)&f0[k];
          float4 B = *(const float4*)&f1[k];
          xa0 += A.x*wl0[k]  + A.y*wl0[k+1]  + A.z*wl0[k+2]  + A.w*wl0[k+3];
          xa1 += A.x*wl1c[k] + A.y*wl1c[k+1] + A.z*wl1c[k+2] + A.w*wl1c[k+3];
          xb0 += B.x*wl0[k]  + B.y*wl0[k+1]  + B.z*wl0[k+2]  + B.w*wl0[k+3];
          xb1 += B.x*wl1c[k] + B.y*wl1c[k+1] + B.z*wl1c[k+2] + B.w*wl1c[k+3];
        }
        float ta = lrelu(xa0 + xr0)*at0 + lrelu(xa1 + xr1)*at1;
        float tc = lrelu(xb0 + xr0)*at0 + lrelu(xb1 + xr1)*at1;
        ta += __shfl_xor(ta,1); tc += __shfl_xor(tc,1);
        ta += __shfl_xor(ta,2); tc += __shfl_xor(tc,2);
        ta += __shfl_xor(ta,4); tc += __shfl_xor(tc,4);
        ta += __shfl_xor(ta,8); tc += __shfl_xor(tc,8);
        if ((lane & 15) == 0){ tbw[4*j + head] = ta; tbw[4*(j+1) + head] = tc; }
      }
      if (j < nj){
        const int u0 = (j == 0) ? v : snbr[i][j-1];
        const float* f0 = &nfa[u0*F_];
        float xa0=0,xa1=0;
        #pragma unroll
        for (int k = 0; k < F_; k += 4){
          float4 A = *(const float4*)&f0[k];
          xa0 += A.x*wl0[k]  + A.y*wl0[k+1]  + A.z*wl0[k+2]  + A.w*wl0[k+3];
          xa1 += A.x*wl1c[k] + A.y*wl1c[k+1] + A.z*wl1c[k+2] + A.w*wl1c[k+3];
        }
        float ta = lrelu(xa0 + xr0)*at0 + lrelu(xa1 + xr1)*at1;
        ta += __shfl_xor(ta,1); ta += __shfl_xor(ta,2);
        ta += __shfl_xor(ta,4); ta += __shfl_xor(ta,8);
        if ((lane & 15) == 0) tbw[4*j + head] = ta;
      }

      // per-head max & sum (exactly the reference's segment_max / segment_sum)
      float mloc = -INFINITY;
      for (int q = (lane & 15); q < nj; q += 16) mloc = fmaxf(mloc, tbw[4*q + head]);
      mloc = fmaxf(mloc, __shfl_xor(mloc,1));
      mloc = fmaxf(mloc, __shfl_xor(mloc,2));
      mloc = fmaxf(mloc, __shfl_xor(mloc,4));
      mloc = fmaxf(mloc, __shfl_xor(mloc,8));
      float sloc = 0.f;
      for (int q = (lane & 15); q < nj; q += 16) sloc += expf(tbw[4*q + head] - mloc);
      sloc += __shfl_xor(sloc,1); sloc += __shfl_xor(sloc,2);
      sloc += __shfl_xor(sloc,4); sloc += __shfl_xor(sloc,8);
      const float inv = 1.0f/sloc;

      // pass 2 (pairwise): weighted sum of xl
      float ac0 = 0.f, ac1 = 0.f;
      j = 0;
      for (; j + 2 <= nj; j += 2){
        const int u0 = (j == 0) ? v : snbr[i][j-1];
        const int u1 = snbr[i][j];
        const float* f0 = &nfa[u0*F_];
        const float* f1 = &nfa[u1*F_];
        float xa0=0,xa1=0,xb0=0,xb1=0;
        #pragma unroll
        for (int k = 0; k < F_; k += 4){
          float4 A = *(const float4*)&f0[k];
          float4 B = *(const float4*)&f1[k];
          xa0 += A.x*wl0[k]  + A.y*wl0[k+1]  + A.z*wl0[k+2]  + A.w*wl0[k+3];
          xa1 += A.x*wl1c[k] + A.y*wl1c[k+1] + A.z*wl1c[k+2] + A.w*wl1c[k+3];
          xb0 += B.x*wl0[k]  + B.y*wl0[k+1]  + B.z*wl0[k+2]  + B.w*wl0[k+3];
          xb1 += B.x*wl1c[k] + B.y*wl1c[k+1] + B.z*wl1c[k+2] + B.w*wl1c[k+3];
        }
        const float aa = expf(tbw[4*j + head]     - mloc)*inv;
        const float ab = expf(tbw[4*(j+1) + head] - mloc)*inv;
        ac0 += aa*xa0 + ab*xb0;
        ac1 += aa*xa1 + ab*xb1;
      }
      if (j < nj){
        const int u0 = (j == 0) ? v : snbr[i][j-1];
        const float* f0 = &nfa[u0*F_];
        float xa0=0,xa1=0;
        #pragma unroll
        for (int k = 0; k < F_; k += 4){
          float4 A = *(const float4*)&f0[k];
          xa0 += A.x*wl0[k]  + A.y*wl0[k+1]  + A.z*wl0[k+2]  + A.w*wl0[k+3];
          xa1 += A.x*wl1c[k] + A.y*wl1c[k+1] + A.z*wl1c[k+2] + A.w*wl1c[k+3];
        }
        const float aa = expf(tbw[4*j + head] - mloc)*inv;
        ac0 += aa*xa0; ac1 += aa*xa1;
      }

      // bias + LayerNorm over 128 + ReLU
      float v0 = ac0 + b1[c0], v1 = ac1 + b1[c0+1];
      float ss = v0 + v1;
      ss += __shfl_xor(ss,1); ss += __shfl_xor(ss,2); ss += __shfl_xor(ss,4);
      ss += __shfl_xor(ss,8); ss += __shfl_xor(ss,16); ss += __shfl_xor(ss,32);
      float mu = ss*(1.0f/D_);
      float d0 = v0 - mu, d1 = v1 - mu;
      float vs = d0*d0 + d1*d1;
      vs += __shfl_xor(vs,1); vs += __shfl_xor(vs,2); vs += __shfl_xor(vs,4);
      vs += __shfl_xor(vs,8); vs += __shfl_xor(vs,16); vs += __shfl_xor(vs,32);
      float rinv = rsqrtf(vs*(1.0f/D_) + 1e-5f);
      float h0 = fmaxf(d0*rinv*lnw[c0]   + lnb[c0],   0.0f);
      float h1 = fmaxf(d1*rinv*lnw[c0+1] + lnb[c0+1], 0.0f);
      *(float2*)&hrow[i][c0] = make_float2(h0, h1);
    }
  }
  __syncthreads();                                   // S4

  // ---- P4: xl2 per owner slot (Wl2 streamed from L2, coalesced); slot 0 also does xr2
  for (int i = wv; i < ns; i += 16){
    if (alias_[i] != -1) continue;
    float acc0 = 0.f, acc1 = 0.f, axr0 = 0.f, axr1 = 0.f;
    if (i == 0){
      #pragma unroll 8
      for (int k = 0; k < D_; ++k){
        const float hk = hrow[0][k];
        float2 wa = *(const float2*)&Wl2[k*D_ + c0];
        float2 wb = *(const float2*)&Wr2[k*D_ + c0];
        acc0 += hk*wa.x; acc1 += hk*wa.y;
        axr0 += hk*wb.x; axr1 += hk*wb.y;
      }
      *(float2*)&xr2s[c0] = make_float2(axr0, axr1);
    } else {
      #pragma unroll 8
      for (int k = 0; k < D_; ++k){
        const float hk = hrow[i][k];
        float2 wa = *(const float2*)&Wl2[k*D_ + c0];
        acc0 += hk*wa.x; acc1 += hk*wa.y;
      }
    }
    *(float2*)&hrow[i][c0] = make_float2(acc0, acc1);   // in-place: reads done above
  }
  __syncthreads();                                   // S5

  // ---- P5: layer-2 attention at agent node (wave 0), two-pass
  if (wv == 0){
    const float2 xr = *(const float2*)&xr2s[c0];
    const float at20 = att2[c0], at21 = att2[c0+1];
    float* tbw = tb[0];
    int i = 0;
    for (; i + 2 <= ns; i += 2){
      const int o0 = (alias_[i]   < 0) ? i   : alias_[i];
      const int o1 = (alias_[i+1] < 0) ? i+1 : alias_[i+1];
      float2 x0 = *(const float2*)&hrow[o0][c0];
      float2 x1 = *(const float2*)&hrow[o1][c0];
      float t0 = lrelu(x0.x + xr.x)*at20 + lrelu(x0.y + xr.y)*at21;
      float t1 = lrelu(x1.x + xr.x)*at20 + lrelu(x1.y + xr.y)*at21;
      t0 += __shfl_xor(t0,1);  t1 += __shfl_xor(t1,1);
      t0 += __shfl_xor(t0,2);  t1 += __shfl_xor(t1,2);
      t0 += __shfl_xor(t0,4);  t1 += __shfl_xor(t1,4);
      t0 += __shfl_xor(t0,8);  t1 += __shfl_xor(t1,8);
      t0 += __shfl_xor(t0,16); t1 += __shfl_xor(t1,16);
      t0 += __shfl_xor(t0,32); t1 += __shfl_xor(t1,32);
      if (lane == 0){ tbw[i] = t0; tbw[i+1] = t1; }
    }
    if (i < ns){
      const int o0 = (alias_[i] < 0) ? i : alias_[i];
      float2 x0 = *(const float2*)&hrow[o0][c0];
      float t0 = lrelu(x0.x + xr.x)*at20 + lrelu(x0.y + xr.y)*at21;
      t0 += __shfl_xor(t0,1);  t0 += __shfl_xor(t0,2);  t0 += __shfl_xor(t0,4);
      t0 += __shfl_xor(t0,8);  t0 += __shfl_xor(t0,16); t0 += __shfl_xor(t0,32);
      if (lane == 0) tbw[i] = t0;
    }
    float mloc = -INFINITY;
    for (int q = lane; q < ns; q += 64) mloc = fmaxf(mloc, tbw[q]);
    mloc = fmaxf(mloc, __shfl_xor(mloc,1));  mloc = fmaxf(mloc, __shfl_xor(mloc,2));
    mloc = fmaxf(mloc, __shfl_xor(mloc,4));  mloc = fmaxf(mloc, __shfl_xor(mloc,8));
    mloc = fmaxf(mloc, __shfl_xor(mloc,16)); mloc = fmaxf(mloc, __shfl_xor(mloc,32));
    float sloc = 0.f;
    for (int q = lane; q < ns; q += 64) sloc += expf(tbw[q] - mloc);
    sloc += __shfl_xor(sloc,1);  sloc += __shfl_xor(sloc,2);
    sloc += __shfl_xor(sloc,4);  sloc += __shfl_xor(sloc,8);
    sloc += __shfl_xor(sloc,16); sloc += __shfl_xor(sloc,32);
    const float inv = 1.0f/sloc;
    float a0 = 0.f, a1 = 0.f;
    for (int q = 0; q < ns; ++q){
      const int o = (alias_[q] < 0) ? q : alias_[q];
      float2 xl = *(const float2*)&hrow[o][c0];
      const float al = expf(tbw[q] - mloc)*inv;
      a0 += al*xl.x; a1 += al*xl.y;
    }
    afl[c0]   = a0 + b2[c0];
    afl[c0+1] = a1 + b2[c0+1];
  }
  __syncthreads();                                   // S6

  // ---- P6: gi half of the GRU (gh is already in gbuf[384..767])
  if (tid < 3*D_){
    const float* wrow = &Wih[tid*D_];
    float acc = bih[tid];
    #pragma unroll 8
    for (int k = 0; k < D_; ++k) acc += afl[k]*wrow[k];
    gbuf[tid] = acc;
  }
  __syncthreads();                                   // S7
  if (tid < D_){
    float r = sigm(gbuf[tid]         + gbuf[3*D_ + tid]);
    float z = sigm(gbuf[D_ + tid]    + gbuf[4*D_ + tid]);
    float n = tanhf(gbuf[2*D_ + tid] + r*gbuf[5*D_ + tid]);
    float nv = (1.0f - z)*n + z*hsl[tid];
    nhl[tid] = nv;
    out[272 + a*D_ + tid] = nv;                      // next_h
  }
  __syncthreads();                                   // S8
  if (tid < 16){
    float lg = ba[tid];
    #pragma unroll 8
    for (int k = 0; k < D_; ++k) lg += nhl[k]*Wa[k*16 + tid];
    if (am[a*16 + tid] == 0) lg = -1e8f;
    out[a*16 + tid] = lg;                            // logits
  } else if (tid == 16){
    float v = bv[0];
    #pragma unroll 8
    for (int k = 0; k < D_; ++k) v += nhl[k]*Wv[k];
    out[256 + a] = v;                                // values
  }
}

// ---------------------------------------------------------------------------
extern "C" void kernel_launch(void* const* d_in, const int* in_sizes, int n_in,
                              void* d_out, int out_size, void* d_ws, size_t ws_size,
                              hipStream_t stream){
  const float* nf   = (const float*)d_in[0];
  const int*   ei   = (const int*)  d_in[1];
  const float* hs   = (const float*)d_in[2];
  const int*   am   = (const int*)  d_in[3];
  const float* Wl1  = (const float*)d_in[4];
  const float* Wr1  = (const float*)d_in[5];
  const float* att1 = (const float*)d_in[6];
  const float* b1   = (const float*)d_in[7];
  const float* lnw  = (const float*)d_in[8];
  const float* lnb  = (const float*)d_in[9];
  const float* Wl2  = (const float*)d_in[10];
  const float* Wr2  = (const float*)d_in[11];
  const float* att2 = (const float*)d_in[12];
  const float* b2   = (const float*)d_in[13];
  const float* Wih  = (const float*)d_in[14];
  const float* Whh  = (const float*)d_in[15];
  const float* bih  = (const float*)d_in[16];
  const float* bhh  = (const float*)d_in[17];
  const float* Wa   = (const float*)d_in[18];
  const float* ba   = (const float*)d_in[19];
  const float* Wv   = (const float*)d_in[20];
  const float* bv   = (const float*)d_in[21];
  float* out = (float*)d_out;

  k_fused<<<A_, 1024, 0, stream>>>(nf, ei, hs, am, Wl1, Wr1, att1, b1, lnw, lnb,
                                   Wl2, Wr2, att2, b2, Wih, Whh, bih, bhh,
                                   Wa, ba, Wv, bv, out);
}

// Round 6
// 59.631 us; speedup vs baseline: 1.6159x; 1.6159x over previous
//
#include <hip/hip_runtime.h>
#include <math.h>

#define A_    16
#define N_    1000
#define F_    16
#define E_    16000
#define D_    128
#define CAP_  48          // max tracked in-degree (Binomial mean 16, ~8 sigma safe)
#define MAXS  49          // slot 0 = self, 1..48 = in-edges of agent node
#define NB_A1 196         // attn1 blocks: 784 waves = 16*49
#define NB_GH 24          // gh blocks: 6144 = 16*384 row-dots

__device__ __forceinline__ float lrelu(float v){ return v > 0.0f ? v : 0.2f*v; }
__device__ __forceinline__ float sigm(float x){ return 1.0f/(1.0f + expf(-x)); }

// ---- K1: zero counters + find agent node per graph (one memory round) ----
__global__ void k_init(const float* __restrict__ nf, int* __restrict__ ncount,
                       int* __restrict__ agent_node){
  int t = blockIdx.x*256 + threadIdx.x;
  if (t < N_) ncount[t] = 0;
  if (t < A_*N_ && nf[(size_t)t*F_] == 1.0f) agent_node[t/N_] = t%N_;
}

// ---- K2: one edge per thread -> inverted adjacency (agent-independent) ----
__global__ void k_scan(const int* __restrict__ ei, int* __restrict__ ncount,
                       int* __restrict__ nbrs){
  int e = blockIdx.x*256 + threadIdx.x;
  if (e >= E_) return;
  int src = ei[e], dst = ei[E_ + e];
  int p = atomicAdd(&ncount[dst], 1);
  if (p < CAP_) nbrs[dst*CAP_ + p] = src;
}

// ---- K3: layer-1 GATv2 (4x32) + LN + ReLU, wave per (agent,slot);
//          blocks >= NB_A1 compute the Whh half of the GRU ----------------
__global__ void __launch_bounds__(256) k_attn1(
    const float* __restrict__ nf, const int* __restrict__ agent_node,
    const int* __restrict__ ncount, const int* __restrict__ nbrs,
    const float* __restrict__ Wl1, const float* __restrict__ Wr1,
    const float* __restrict__ att1, const float* __restrict__ b1,
    const float* __restrict__ lnw, const float* __restrict__ lnb,
    const float* __restrict__ hs, const float* __restrict__ Whh,
    const float* __restrict__ bhh,
    float* __restrict__ h_c, float* __restrict__ ghb){
  const int tid = threadIdx.x;

  if (blockIdx.x >= NB_A1){           // ---- gh = bhh + Whh @ rnn_state
    int t = (blockIdx.x - NB_A1)*256 + tid;     // 0..6143
    int a = t/384, r = t - a*384;
    const float4* w4 = (const float4*)&Whh[r*D_];
    const float4* x4 = (const float4*)&hs[a*D_];
    float acc = bhh[r];
    #pragma unroll
    for (int k = 0; k < D_/4; ++k){
      float4 w = w4[k], x = x4[k];
      acc += w.x*x.x + w.y*x.y + w.z*x.z + w.w*x.w;
    }
    ghb[a*384 + r] = acc;
    return;
  }

  const int lane = tid & 63;
  const int wv   = tid >> 6;
  const int wid  = blockIdx.x*4 + wv;
  const int a = wid / MAXS;
  const int i = wid - a*MAXS;
  const int d_a  = agent_node[a];
  const int dega = min(ncount[d_a], CAP_);
  if (i > dega) return;
  const int v   = (i == 0) ? d_a : nbrs[d_a*CAP_ + (i-1)];
  const int deg = min(ncount[v], CAP_);
  const int c0  = lane*2;

  __shared__ float feat[4][MAXS*F_];
  float* fb = feat[wv];

  int nid = (lane < deg) ? nbrs[v*CAP_ + lane] : 0;
  for (int t = lane; t < (deg+1)*4; t += 64){     // stage rows: 0=self,1..deg
    int j = t >> 2, q = (t & 3)*4;
    int s = (j == 0) ? v : __shfl(nid, j-1);
    *(float4*)&fb[j*F_ + q] = *(const float4*)&nf[((size_t)a*N_ + s)*F_ + q];
  }
  asm volatile("s_waitcnt lgkmcnt(0)" ::: "memory");

  float wl0[F_], wl1c[F_];
  #pragma unroll
  for (int k = 0; k < F_; ++k){
    float2 w = *(const float2*)&Wl1[k*D_ + c0];
    wl0[k] = w.x; wl1c[k] = w.y;
  }
  float xr0 = 0.f, xr1 = 0.f;
  #pragma unroll
  for (int k = 0; k < F_; ++k){
    float2 w = *(const float2*)&Wr1[k*D_ + c0];
    float xv = fb[k];
    xr0 += xv*w.x; xr1 += xv*w.y;
  }
  const int head = lane >> 4;
  const float at0 = att1[head*32 + (c0 & 31)];
  const float at1 = att1[head*32 + ((c0+1) & 31)];

  float m = -INFINITY, ls = 0.f, ac0 = 0.f, ac1 = 0.f;
  for (int j = 0; j <= deg; ++j){
    const float* fr = &fb[j*F_];
    float xl0 = 0.f, xl1 = 0.f;
    #pragma unroll
    for (int k = 0; k < F_; k += 4){
      float4 xv = *(const float4*)&fr[k];
      xl0 += xv.x*wl0[k]  + xv.y*wl0[k+1]  + xv.z*wl0[k+2]  + xv.w*wl0[k+3];
      xl1 += xv.x*wl1c[k] + xv.y*wl1c[k+1] + xv.z*wl1c[k+2] + xv.w*wl1c[k+3];
    }
    float t = lrelu(xl0 + xr0)*at0 + lrelu(xl1 + xr1)*at1;
    t += __shfl_xor(t,1); t += __shfl_xor(t,2);
    t += __shfl_xor(t,4); t += __shfl_xor(t,8);         // 16-lane head groups
    float mn = fmaxf(m, t);
    float sc = expf(m - mn), p = expf(t - mn);
    ls = ls*sc + p; ac0 = ac0*sc + p*xl0; ac1 = ac1*sc + p*xl1;
    m = mn;
  }
  float inv = 1.0f/ls;
  float v0 = ac0*inv + b1[c0], v1 = ac1*inv + b1[c0+1];
  float ss = v0 + v1;
  ss += __shfl_xor(ss,1); ss += __shfl_xor(ss,2); ss += __shfl_xor(ss,4);
  ss += __shfl_xor(ss,8); ss += __shfl_xor(ss,16); ss += __shfl_xor(ss,32);
  float mu = ss*(1.0f/D_);
  float d0 = v0 - mu, d1 = v1 - mu;
  float vs = d0*d0 + d1*d1;
  vs += __shfl_xor(vs,1); vs += __shfl_xor(vs,2); vs += __shfl_xor(vs,4);
  vs += __shfl_xor(vs,8); vs += __shfl_xor(vs,16); vs += __shfl_xor(vs,32);
  float rinv = rsqrtf(vs*(1.0f/D_) + 1e-5f);
  float h0 = fmaxf(d0*rinv*lnw[c0]   + lnb[c0],   0.0f);
  float h1 = fmaxf(d1*rinv*lnw[c0+1] + lnb[c0+1], 0.0f);
  *(float2*)&h_c[((size_t)a*MAXS + i)*D_ + c0] = make_float2(h0, h1);
}

// ---- K4: per-agent tail: gemm2 + attn2 + gi + GRU + heads ----------------
__global__ void __launch_bounds__(1024) k_tail(
    const float* __restrict__ h_c, const float* __restrict__ ghb,
    const int* __restrict__ agent_node, const int* __restrict__ ncount,
    const float* __restrict__ hs, const int* __restrict__ am,
    const float* __restrict__ Wl2, const float* __restrict__ Wr2,
    const float* __restrict__ att2, const float* __restrict__ b2,
    const float* __restrict__ Wih, const float* __restrict__ bih,
    const float* __restrict__ Wa, const float* __restrict__ ba,
    const float* __restrict__ Wv, const float* __restrict__ bv,
    float* __restrict__ out){
  const int a    = blockIdx.x;
  const int tid  = threadIdx.x;
  const int lane = tid & 63;
  const int wv   = tid >> 6;

  __shared__ float hsl2[MAXS][D_];     // h1 rows, overwritten in-place by xl2
  __shared__ float xr2s[D_], afl[D_], ghl[3*D_], gbuf[3*D_], hsrow[D_], nh[D_];
  __shared__ float scores[64];

  const int d_a = agent_node[a];
  const int ns  = min(ncount[d_a], CAP_) + 1;

  // T0: stage h rows + gh + rnn_state
  for (int t = tid; t < ns*(D_/4); t += 1024){
    int j = t >> 5, q = t & 31;
    ((float4*)hsl2[j])[q] = ((const float4*)&h_c[((size_t)a*MAXS + j)*D_])[q];
  }
  if (tid < D_) hsrow[tid] = hs[a*D_ + tid];
  if (tid >= D_ && tid < D_ + 3*D_) ghl[tid - D_] = ghb[a*384 + (tid - D_)];
  __syncthreads();

  // T1: xl2 for all slots + xr2, 8 col-groups x 7 static jobs
  {
    const int g = tid >> 7, c = tid & (D_-1);
    const bool hasXr = ((ns & 7) == g);
    float acc[7];
    #pragma unroll
    for (int jj = 0; jj < 7; ++jj) acc[jj] = 0.f;
    for (int k = 0; k < D_; k += 4){
      float w0 = Wl2[(k+0)*D_ + c], w1 = Wl2[(k+1)*D_ + c];
      float w2 = Wl2[(k+2)*D_ + c], w3 = Wl2[(k+3)*D_ + c];
      float r0 = 0.f, r1 = 0.f, r2 = 0.f, r3 = 0.f;
      if (hasXr){
        r0 = Wr2[(k+0)*D_ + c]; r1 = Wr2[(k+1)*D_ + c];
        r2 = Wr2[(k+2)*D_ + c]; r3 = Wr2[(k+3)*D_ + c];
      }
      #pragma unroll
      for (int jj = 0; jj < 7; ++jj){
        const int J = g + jj*8;
        if (J < ns){
          float4 h4 = *(const float4*)&hsl2[J][k];
          acc[jj] += h4.x*w0 + h4.y*w1 + h4.z*w2 + h4.w*w3;
        } else if (J == ns){
          float4 h4 = *(const float4*)&hsl2[0][k];
          acc[jj] += h4.x*r0 + h4.y*r1 + h4.z*r2 + h4.w*r3;
        }
      }
    }
    __syncthreads();                       // all reads of h done
    #pragma unroll
    for (int jj = 0; jj < 7; ++jj){
      const int J = g + jj*8;
      if (J < ns)       hsl2[J][c] = acc[jj];
      else if (J == ns) xr2s[c]    = acc[jj];
    }
  }
  __syncthreads();

  // T2a: attention scores, wave w handles slots w, w+16, w+32, w+48
  {
    const int c0 = lane*2;
    const float xr0 = xr2s[c0], xr1 = xr2s[c0+1];
    const float at0 = att2[c0], at1 = att2[c0+1];
    for (int q = 0; q < 4; ++q){
      const int s = wv + q*16;
      if (s < ns){
        float2 xl = *(const float2*)&hsl2[s][c0];
        float t = lrelu(xl.x + xr0)*at0 + lrelu(xl.y + xr1)*at1;
        t += __shfl_xor(t,1);  t += __shfl_xor(t,2);  t += __shfl_xor(t,4);
        t += __shfl_xor(t,8);  t += __shfl_xor(t,16); t += __shfl_xor(t,32);
        if (lane == 0) scores[s] = t;
      }
    }
  }
  __syncthreads();
  // T2b: softmax over ns scores (wave 0, lane-parallel)
  if (wv == 0){
    float sc = (lane < ns) ? scores[lane] : -INFINITY;
    float m = sc;
    m = fmaxf(m, __shfl_xor(m,1));  m = fmaxf(m, __shfl_xor(m,2));
    m = fmaxf(m, __shfl_xor(m,4));  m = fmaxf(m, __shfl_xor(m,8));
    m = fmaxf(m, __shfl_xor(m,16)); m = fmaxf(m, __shfl_xor(m,32));
    float p = (lane < ns) ? expf(sc - m) : 0.f;
    float s = p;
    s += __shfl_xor(s,1);  s += __shfl_xor(s,2);  s += __shfl_xor(s,4);
    s += __shfl_xor(s,8);  s += __shfl_xor(s,16); s += __shfl_xor(s,32);
    if (lane < ns) scores[lane] = p/s;           // alpha
  }
  __syncthreads();
  // T2c: weighted sum -> afl
  if (tid < D_){
    float acc = 0.f;
    for (int i = 0; i < ns; ++i) acc += scores[i]*hsl2[i][tid];
    afl[tid] = acc + b2[tid];
  }
  __syncthreads();

  // T3: gi = bih + Wih @ afl (row per thread, float4)
  if (tid < 3*D_){
    const float4* w4 = (const float4*)&Wih[tid*D_];
    float acc = bih[tid];
    #pragma unroll
    for (int k = 0; k < D_/4; ++k){
      float4 w = w4[k];
      float4 x = *(const float4*)&afl[k*4];
      acc += w.x*x.x + w.y*x.y + w.z*x.z + w.w*x.w;
    }
    gbuf[tid] = acc;
  }
  __syncthreads();

  // T4: GRU elementwise
  if (tid < D_){
    float r = sigm(gbuf[tid]         + ghl[tid]);
    float z = sigm(gbuf[D_ + tid]    + ghl[D_ + tid]);
    float n = tanhf(gbuf[2*D_ + tid] + r*ghl[2*D_ + tid]);
    float nv = (1.0f - z)*n + z*hsrow[tid];
    nh[tid] = nv;
    out[272 + a*D_ + tid] = nv;                  // next_h
  }
  __syncthreads();

  // T5: heads
  if (tid < 16){
    float lg = ba[tid];
    #pragma unroll 8
    for (int k = 0; k < D_; ++k) lg += nh[k]*Wa[k*16 + tid];
    if (am[a*16 + tid] == 0) lg = -1e8f;
    out[a*16 + tid] = lg;                        // logits
  } else if (tid == 16){
    float v = bv[0];
    #pragma unroll 8
    for (int k = 0; k < D_; ++k) v += nh[k]*Wv[k];
    out[256 + a] = v;                            // values
  }
}

// ---------------------------------------------------------------------------
extern "C" void kernel_launch(void* const* d_in, const int* in_sizes, int n_in,
                              void* d_out, int out_size, void* d_ws, size_t ws_size,
                              hipStream_t stream){
  const float* nf   = (const float*)d_in[0];
  const int*   ei   = (const int*)  d_in[1];
  const float* hs   = (const float*)d_in[2];
  const int*   am   = (const int*)  d_in[3];
  const float* Wl1  = (const float*)d_in[4];
  const float* Wr1  = (const float*)d_in[5];
  const float* att1 = (const float*)d_in[6];
  const float* b1   = (const float*)d_in[7];
  const float* lnw  = (const float*)d_in[8];
  const float* lnb  = (const float*)d_in[9];
  const float* Wl2  = (const float*)d_in[10];
  const float* Wr2  = (const float*)d_in[11];
  const float* att2 = (const float*)d_in[12];
  const float* b2   = (const float*)d_in[13];
  const float* Wih  = (const float*)d_in[14];
  const float* Whh  = (const float*)d_in[15];
  const float* bih  = (const float*)d_in[16];
  const float* bhh  = (const float*)d_in[17];
  const float* Wa   = (const float*)d_in[18];
  const float* ba   = (const float*)d_in[19];
  const float* Wv   = (const float*)d_in[20];
  const float* bv   = (const float*)d_in[21];
  float* out = (float*)d_out;

  char* ws = (char*)d_ws;
  float* h_c        = (float*)(ws);               // 16*49*128 f32 = 401408 B
  float* ghb        = (float*)(ws + 401408);      // 16*384 f32   = 24576 B
  int*   agent_node = (int*)  (ws + 425984);      // 64 B
  int*   ncount     = (int*)  (ws + 426048);      // 4000 B
  int*   nbrs       = (int*)  (ws + 430080);      // 1000*48*4 = 192000 B

  k_init <<<64, 256, 0, stream>>>(nf, ncount, agent_node);
  k_scan <<<63, 256, 0, stream>>>(ei, ncount, nbrs);
  k_attn1<<<NB_A1 + NB_GH, 256, 0, stream>>>(nf, agent_node, ncount, nbrs,
                                             Wl1, Wr1, att1, b1, lnw, lnb,
                                             hs, Whh, bhh, h_c, ghb);
  k_tail <<<A_, 1024, 0, stream>>>(h_c, ghb, agent_node, ncount, hs, am,
                                   Wl2, Wr2, att2, b2, Wih, bih,
                                   Wa, ba, Wv, bv, out);
}

// Round 7
// 47.385 us; speedup vs baseline: 2.0336x; 1.2584x over previous
//
#include <hip/hip_runtime.h>
#include <math.h>

#define A_    16
#define N_    1000
#define F_    16
#define E_    16000
#define D_    128
#define CAP_  48          // max tracked in-degree (Binomial mean 16, ~8 sigma safe)
#define MAXS  49          // slot 0 = self, 1..48 = in-edges of agent node
#define NB_A1 196         // attn1 blocks: 784 waves = 16*49
#define NB_GH 24          // gh blocks: 6144 = 16*384 row-dots

__device__ __forceinline__ float lrelu(float v){ return v > 0.0f ? v : 0.2f*v; }
__device__ __forceinline__ float sigm(float x){ return 1.0f/(1.0f + expf(-x)); }

// ---- K1: zero counters + find agent node per graph (one memory round) ----
__global__ void k_init(const float* __restrict__ nf, int* __restrict__ ncount,
                       int* __restrict__ agent_node){
  int t = blockIdx.x*256 + threadIdx.x;
  if (t < N_) ncount[t] = 0;
  if (t < A_*N_ && nf[(size_t)t*F_] == 1.0f) agent_node[t/N_] = t%N_;
}

// ---- K2: one edge per thread -> inverted adjacency (agent-independent) ----
__global__ void k_scan(const int* __restrict__ ei, int* __restrict__ ncount,
                       int* __restrict__ nbrs){
  int e = blockIdx.x*256 + threadIdx.x;
  if (e >= E_) return;
  int src = ei[e], dst = ei[E_ + e];
  int p = atomicAdd(&ncount[dst], 1);
  if (p < CAP_) nbrs[dst*CAP_ + p] = src;
}

// ---- K3: layer-1 GATv2 (4x32) + LN + ReLU, wave per (agent,slot);
//          blocks >= NB_A1 compute the Whh half of the GRU ----------------
__global__ void __launch_bounds__(256) k_attn1(
    const float* __restrict__ nf, const int* __restrict__ agent_node,
    const int* __restrict__ ncount, const int* __restrict__ nbrs,
    const float* __restrict__ Wl1, const float* __restrict__ Wr1,
    const float* __restrict__ att1, const float* __restrict__ b1,
    const float* __restrict__ lnw, const float* __restrict__ lnb,
    const float* __restrict__ hs, const float* __restrict__ Whh,
    const float* __restrict__ bhh,
    float* __restrict__ h_c, float* __restrict__ ghb){
  const int tid = threadIdx.x;

  if (blockIdx.x >= NB_A1){           // ---- gh = bhh + Whh @ rnn_state
    int t = (blockIdx.x - NB_A1)*256 + tid;     // 0..6143
    int a = t/384, r = t - a*384;
    const float4* w4 = (const float4*)&Whh[r*D_];
    const float4* x4 = (const float4*)&hs[a*D_];
    float acc = bhh[r];
    #pragma unroll
    for (int k = 0; k < D_/4; ++k){
      float4 w = w4[k], x = x4[k];
      acc += w.x*x.x + w.y*x.y + w.z*x.z + w.w*x.w;
    }
    ghb[a*384 + r] = acc;
    return;
  }

  const int lane = tid & 63;
  const int wv   = tid >> 6;
  const int wid  = blockIdx.x*4 + wv;
  const int a = wid / MAXS;
  const int i = wid - a*MAXS;
  const int d_a  = agent_node[a];
  const int dega = min(ncount[d_a], CAP_);
  if (i > dega) return;
  const int v   = (i == 0) ? d_a : nbrs[d_a*CAP_ + (i-1)];
  const int deg = min(ncount[v], CAP_);
  const int c0  = lane*2;

  __shared__ float feat[4][MAXS*F_];
  float* fb = feat[wv];

  int nid = (lane < deg) ? nbrs[v*CAP_ + lane] : 0;
  for (int t = lane; t < (deg+1)*4; t += 64){     // stage rows: 0=self,1..deg
    int j = t >> 2, q = (t & 3)*4;
    int s = (j == 0) ? v : __shfl(nid, j-1);
    *(float4*)&fb[j*F_ + q] = *(const float4*)&nf[((size_t)a*N_ + s)*F_ + q];
  }
  asm volatile("s_waitcnt lgkmcnt(0)" ::: "memory");

  float wl0[F_], wl1c[F_];
  #pragma unroll
  for (int k = 0; k < F_; ++k){
    float2 w = *(const float2*)&Wl1[k*D_ + c0];
    wl0[k] = w.x; wl1c[k] = w.y;
  }
  float xr0 = 0.f, xr1 = 0.f;
  #pragma unroll
  for (int k = 0; k < F_; ++k){
    float2 w = *(const float2*)&Wr1[k*D_ + c0];
    float xv = fb[k];
    xr0 += xv*w.x; xr1 += xv*w.y;
  }
  const int head = lane >> 4;
  const float at0 = att1[head*32 + (c0 & 31)];
  const float at1 = att1[head*32 + ((c0+1) & 31)];

  float m = -INFINITY, ls = 0.f, ac0 = 0.f, ac1 = 0.f;
  for (int j = 0; j <= deg; ++j){
    const float* fr = &fb[j*F_];
    float xl0 = 0.f, xl1 = 0.f;
    #pragma unroll
    for (int k = 0; k < F_; k += 4){
      float4 xv = *(const float4*)&fr[k];
      xl0 += xv.x*wl0[k]  + xv.y*wl0[k+1]  + xv.z*wl0[k+2]  + xv.w*wl0[k+3];
      xl1 += xv.x*wl1c[k] + xv.y*wl1c[k+1] + xv.z*wl1c[k+2] + xv.w*wl1c[k+3];
    }
    float t = lrelu(xl0 + xr0)*at0 + lrelu(xl1 + xr1)*at1;
    t += __shfl_xor(t,1); t += __shfl_xor(t,2);
    t += __shfl_xor(t,4); t += __shfl_xor(t,8);         // 16-lane head groups
    float mn = fmaxf(m, t);
    float sc = expf(m - mn), p = expf(t - mn);
    ls = ls*sc + p; ac0 = ac0*sc + p*xl0; ac1 = ac1*sc + p*xl1;
    m = mn;
  }
  float inv = 1.0f/ls;
  float v0 = ac0*inv + b1[c0], v1 = ac1*inv + b1[c0+1];
  float ss = v0 + v1;
  ss += __shfl_xor(ss,1); ss += __shfl_xor(ss,2); ss += __shfl_xor(ss,4);
  ss += __shfl_xor(ss,8); ss += __shfl_xor(ss,16); ss += __shfl_xor(ss,32);
  float mu = ss*(1.0f/D_);
  float d0 = v0 - mu, d1 = v1 - mu;
  float vs = d0*d0 + d1*d1;
  vs += __shfl_xor(vs,1); vs += __shfl_xor(vs,2); vs += __shfl_xor(vs,4);
  vs += __shfl_xor(vs,8); vs += __shfl_xor(vs,16); vs += __shfl_xor(vs,32);
  float rinv = rsqrtf(vs*(1.0f/D_) + 1e-5f);
  float h0 = fmaxf(d0*rinv*lnw[c0]   + lnb[c0],   0.0f);
  float h1 = fmaxf(d1*rinv*lnw[c0+1] + lnb[c0+1], 0.0f);
  *(float2*)&h_c[((size_t)a*MAXS + i)*D_ + c0] = make_float2(h0, h1);
}

// ---- K4: per-agent tail: gemm2 + attn2 + gi + GRU + heads ----------------
__global__ void __launch_bounds__(1024) k_tail(
    const float* __restrict__ h_c, const float* __restrict__ ghb,
    const int* __restrict__ agent_node, const int* __restrict__ ncount,
    const float* __restrict__ hs, const int* __restrict__ am,
    const float* __restrict__ Wl2, const float* __restrict__ Wr2,
    const float* __restrict__ att2, const float* __restrict__ b2,
    const float* __restrict__ Wih, const float* __restrict__ bih,
    const float* __restrict__ Wa, const float* __restrict__ ba,
    const float* __restrict__ Wv, const float* __restrict__ bv,
    float* __restrict__ out){
  const int a    = blockIdx.x;
  const int tid  = threadIdx.x;
  const int lane = tid & 63;
  const int wv   = tid >> 6;

  __shared__ float hsl2[MAXS][D_];     // h1 rows, overwritten in-place by xl2
  __shared__ float xr2s[D_], afl[D_], ghl[3*D_], gbuf[3*D_], hsrow[D_], nh[D_];
  __shared__ float scores[64];

  const int d_a = agent_node[a];
  const int ns  = min(ncount[d_a], CAP_) + 1;

  // T0: stage h rows + gh + rnn_state
  for (int t = tid; t < ns*(D_/4); t += 1024){
    int j = t >> 5, q = t & 31;
    ((float4*)hsl2[j])[q] = ((const float4*)&h_c[((size_t)a*MAXS + j)*D_])[q];
  }
  if (tid < D_) hsrow[tid] = hs[a*D_ + tid];
  if (tid >= D_ && tid < D_ + 3*D_) ghl[tid - D_] = ghb[a*384 + (tid - D_)];
  __syncthreads();

  // T1: xl2 for all slots + xr2; 64 groups x 16 lanes, lane owns 8 columns.
  //     Each group's 16 lanes read a full 512B weight row per k (coalesced),
  //     256 independent float4 loads per thread -> high MLP.
  {
    const int j  = tid >> 4;             // job 0..63 (need ns+1 <= 50)
    const int c8 = (tid & 15)*8;
    float4 acc0 = make_float4(0,0,0,0), acc1 = make_float4(0,0,0,0);
    if (j <= ns){
      const float* W  = (j == ns) ? Wr2 : Wl2;
      const float* hR = (j == ns) ? hsl2[0] : hsl2[j];
      #pragma unroll 4
      for (int k = 0; k < D_; ++k){
        const float hk = hR[k];
        float4 w0 = *(const float4*)&W[k*D_ + c8];
        float4 w1 = *(const float4*)&W[k*D_ + c8 + 4];
        acc0.x += hk*w0.x; acc0.y += hk*w0.y; acc0.z += hk*w0.z; acc0.w += hk*w0.w;
        acc1.x += hk*w1.x; acc1.y += hk*w1.y; acc1.z += hk*w1.z; acc1.w += hk*w1.w;
      }
    }
    __syncthreads();                     // all reads of h done before overwrite
    if (j < ns){
      *(float4*)&hsl2[j][c8]     = acc0;
      *(float4*)&hsl2[j][c8 + 4] = acc1;
    } else if (j == ns){
      *(float4*)&xr2s[c8]     = acc0;
      *(float4*)&xr2s[c8 + 4] = acc1;
    }
  }
  __syncthreads();

  // T2a: attention scores, wave w handles slots w, w+16, w+32, w+48
  {
    const int c0 = lane*2;
    const float xr0 = xr2s[c0], xr1 = xr2s[c0+1];
    const float at0 = att2[c0], at1 = att2[c0+1];
    for (int q = 0; q < 4; ++q){
      const int s = wv + q*16;
      if (s < ns){
        float2 xl = *(const float2*)&hsl2[s][c0];
        float t = lrelu(xl.x + xr0)*at0 + lrelu(xl.y + xr1)*at1;
        t += __shfl_xor(t,1);  t += __shfl_xor(t,2);  t += __shfl_xor(t,4);
        t += __shfl_xor(t,8);  t += __shfl_xor(t,16); t += __shfl_xor(t,32);
        if (lane == 0) scores[s] = t;
      }
    }
  }
  __syncthreads();
  // T2b: softmax over ns scores (wave 0, lane-parallel)
  if (wv == 0){
    float sc = (lane < ns) ? scores[lane] : -INFINITY;
    float m = sc;
    m = fmaxf(m, __shfl_xor(m,1));  m = fmaxf(m, __shfl_xor(m,2));
    m = fmaxf(m, __shfl_xor(m,4));  m = fmaxf(m, __shfl_xor(m,8));
    m = fmaxf(m, __shfl_xor(m,16)); m = fmaxf(m, __shfl_xor(m,32));
    float p = (lane < ns) ? expf(sc - m) : 0.f;
    float s = p;
    s += __shfl_xor(s,1);  s += __shfl_xor(s,2);  s += __shfl_xor(s,4);
    s += __shfl_xor(s,8);  s += __shfl_xor(s,16); s += __shfl_xor(s,32);
    if (lane < ns) scores[lane] = p/s;           // alpha
  }
  __syncthreads();
  // T2c: weighted sum -> afl
  if (tid < D_){
    float acc = 0.f;
    for (int i = 0; i < ns; ++i) acc += scores[i]*hsl2[i][tid];
    afl[tid] = acc + b2[tid];
  }
  __syncthreads();

  // T3: gi = bih + Wih @ afl — 8 lanes per row, coalesced float4 reads
  #pragma unroll
  for (int p = 0; p < 3; ++p){
    const int r  = p*128 + (tid >> 3);
    const int kk = (tid & 7)*16;
    const float4* w4 = (const float4*)&Wih[r*D_ + kk];
    float acc = 0.f;
    #pragma unroll
    for (int q = 0; q < 4; ++q){
      float4 w = w4[q];
      float4 x = *(const float4*)&afl[kk + q*4];
      acc += w.x*x.x + w.y*x.y + w.z*x.z + w.w*x.w;
    }
    acc += __shfl_xor(acc,1); acc += __shfl_xor(acc,2); acc += __shfl_xor(acc,4);
    if ((tid & 7) == 0) gbuf[r] = acc + bih[r];
  }
  __syncthreads();

  // T4: GRU elementwise
  if (tid < D_){
    float r = sigm(gbuf[tid]         + ghl[tid]);
    float z = sigm(gbuf[D_ + tid]    + ghl[D_ + tid]);
    float n = tanhf(gbuf[2*D_ + tid] + r*ghl[2*D_ + tid]);
    float nv = (1.0f - z)*n + z*hsrow[tid];
    nh[tid] = nv;
    out[272 + a*D_ + tid] = nv;                  // next_h
  }
  __syncthreads();

  // T5: heads, wave-parallel
  if (wv == 0){
    const int j = lane & 15, q = lane >> 4;      // action j, k-quarter q
    float acc = 0.f;
    #pragma unroll 8
    for (int k = q*32; k < q*32 + 32; ++k) acc += nh[k]*Wa[k*16 + j];
    acc += __shfl_xor(acc,16); acc += __shfl_xor(acc,32);
    if (lane < 16){
      float lg = acc + ba[j];
      if (am[a*16 + j] == 0) lg = -1e8f;
      out[a*16 + j] = lg;                        // logits
    }
  } else if (wv == 1){
    const int c0 = lane*2;
    float acc = nh[c0]*Wv[c0] + nh[c0+1]*Wv[c0+1];
    acc += __shfl_xor(acc,1);  acc += __shfl_xor(acc,2);  acc += __shfl_xor(acc,4);
    acc += __shfl_xor(acc,8);  acc += __shfl_xor(acc,16); acc += __shfl_xor(acc,32);
    if (lane == 0) out[256 + a] = acc + bv[0];   // values
  }
}

// ---------------------------------------------------------------------------
extern "C" void kernel_launch(void* const* d_in, const int* in_sizes, int n_in,
                              void* d_out, int out_size, void* d_ws, size_t ws_size,
                              hipStream_t stream){
  const float* nf   = (const float*)d_in[0];
  const int*   ei   = (const int*)  d_in[1];
  const float* hs   = (const float*)d_in[2];
  const int*   am   = (const int*)  d_in[3];
  const float* Wl1  = (const float*)d_in[4];
  const float* Wr1  = (const float*)d_in[5];
  const float* att1 = (const float*)d_in[6];
  const float* b1   = (const float*)d_in[7];
  const float* lnw  = (const float*)d_in[8];
  const float* lnb  = (const float*)d_in[9];
  const float* Wl2  = (const float*)d_in[10];
  const float* Wr2  = (const float*)d_in[11];
  const float* att2 = (const float*)d_in[12];
  const float* b2   = (const float*)d_in[13];
  const float* Wih  = (const float*)d_in[14];
  const float* Whh  = (const float*)d_in[15];
  const float* bih  = (const float*)d_in[16];
  const float* bhh  = (const float*)d_in[17];
  const float* Wa   = (const float*)d_in[18];
  const float* ba   = (const float*)d_in[19];
  const float* Wv   = (const float*)d_in[20];
  const float* bv   = (const float*)d_in[21];
  float* out = (float*)d_out;

  char* ws = (char*)d_ws;
  float* h_c        = (float*)(ws);               // 16*49*128 f32 = 401408 B
  float* ghb        = (float*)(ws + 401408);      // 16*384 f32   = 24576 B
  int*   agent_node = (int*)  (ws + 425984);      // 64 B
  int*   ncount     = (int*)  (ws + 426048);      // 4000 B
  int*   nbrs       = (int*)  (ws + 430080);      // 1000*48*4 = 192000 B

  k_init <<<64, 256, 0, stream>>>(nf, ncount, agent_node);
  k_scan <<<63, 256, 0, stream>>>(ei, ncount, nbrs);
  k_attn1<<<NB_A1 + NB_GH, 256, 0, stream>>>(nf, agent_node, ncount, nbrs,
                                             Wl1, Wr1, att1, b1, lnw, lnb,
                                             hs, Whh, bhh, h_c, ghb);
  k_tail <<<A_, 1024, 0, stream>>>(h_c, ghb, agent_node, ncount, hs, am,
                                   Wl2, Wr2, att2, b2, Wih, bih,
                                   Wa, ba, Wv, bv, out);
}